// Round 7
// baseline (141.387 us; speedup 1.0000x reference)
//
#include <hip/hip_runtime.h>

// ProtoNet head: N=16384 rows, C=128 classes, D=1024 dims, fp32 in/out.
// out = softmax_c( 2*dot(e[n], cent[c]) - ||cent[c]||^2 )  (sq_e dropped: softmax shift-invariant)
// cross term via split-bf16 MFMA: x=hi+lo; x*c ~= hi*chi + hi*clo + lo*chi  (K'=3072 bf16)

#define N_ROWS 16384
#define N_CLS  128
#define N_DIM  1024
#define CSTRIDE 32   // pad atomics: one counter per 128B cache line

// workspace layout (bytes); need ~672 KiB total
#define CNT_OFF 0         // int cnt[128*32]     (16 KiB)
#define SQC_OFF 16384     // float sqc[128*32]   (16 KiB)
#define RL_OFF  32768     // int rowlist[128*256] (128 KiB)
#define BHI_OFF 163840    // bf16 B-frags hi: 32 steps * 8 KiB/step = 256 KiB
#define BLO_OFF 425984    // bf16 B-frags lo: 256 KiB

typedef __attribute__((ext_vector_type(8))) short bf16x8;
typedef __attribute__((ext_vector_type(4))) float f32x4;

// ---------------- kernel 1: labels -> rowlist + padded counts ----------------
__global__ void k_label(const float* __restrict__ y,
                        int* __restrict__ cnt,
                        int* __restrict__ rowlist) {
    int i = blockIdx.x * blockDim.x + threadIdx.x;   // float4 index over N*C/4
    float4 v = ((const float4*)y)[i];
    int base = i * 4;
    int row = base >> 7;          // / C
    int cb  = base & (N_CLS - 1); // % C
    if (v.x > 0.5f) { int s = atomicAdd(&cnt[(cb + 0) * CSTRIDE], 1); if (s < 256) rowlist[(cb + 0) * 256 + s] = row; }
    if (v.y > 0.5f) { int s = atomicAdd(&cnt[(cb + 1) * CSTRIDE], 1); if (s < 256) rowlist[(cb + 1) * 256 + s] = row; }
    if (v.z > 0.5f) { int s = atomicAdd(&cnt[(cb + 2) * CSTRIDE], 1); if (s < 256) rowlist[(cb + 2) * 256 + s] = row; }
    if (v.w > 0.5f) { int s = atomicAdd(&cnt[(cb + 3) * CSTRIDE], 1); if (s < 256) rowlist[(cb + 3) * 256 + s] = row; }
}

// ---- kernel 2: centroids -> packed bf16 hi/lo B-fragments + sq_c ----
// grid (8 d-chunks, 128 classes), 128 threads; thread owns (class c, dim d).
// B-frag for mfma_f32_16x16x32_bf16: elem j of lane l, step gs, col-frag cf
//   = B[k = gs*32 + (l>>4)*8 + j][col = cf*16 + (l&15)]
__global__ void k_centroid(const float* __restrict__ e,
                           const int* __restrict__ cnt,
                           const int* __restrict__ rowlist,
                           unsigned short* __restrict__ bHi,
                           unsigned short* __restrict__ bLo,
                           float* __restrict__ sqc) {
    int c  = blockIdx.y;
    int ch = blockIdx.x;
    int t  = threadIdx.x;
    int d  = ch * 128 + t;
    int n  = cnt[c * CSTRIDE];
    if (n > 256) n = 256;
    const int* rl = rowlist + c * 256;

    float acc = 0.f;
    int i = 0;
    // 16-deep MLP: ~32 KB/CU in flight vs ~9.4 KB needed at HBM latency
    for (; i + 16 <= n; i += 16) {
        float v[16];
        #pragma unroll
        for (int u = 0; u < 16; ++u) v[u] = e[(size_t)rl[i + u] * N_DIM + d];
        float s0 = ((v[0] + v[1]) + (v[2] + v[3])) + ((v[4] + v[5]) + (v[6] + v[7]));
        float s1 = ((v[8] + v[9]) + (v[10] + v[11])) + ((v[12] + v[13]) + (v[14] + v[15]));
        acc += s0 + s1;
    }
    for (; i < n; ++i) acc += e[(size_t)rl[i] * N_DIM + d];

    float val = (n > 0) ? acc / (float)n : 0.f;

    // split val = hi + lo (truncation split; the subtraction is exact)
    unsigned xb = __float_as_uint(val);
    unsigned short hv = (unsigned short)(xb >> 16);
    float hif = __uint_as_float(xb & 0xffff0000u);
    unsigned short lv = (unsigned short)(__float_as_uint(val - hif) >> 16);

    int gs = d >> 5;            // k-step
    int g  = (d >> 3) & 3;      // lane group
    int j  = d & 7;             // element within fragment
    int f  = c >> 4;            // col fragment
    int lb = g * 16 + (c & 15); // lane
    bHi[((gs * 8 + f) * 64 + lb) * 8 + j] = hv;
    bLo[((gs * 8 + f) * 64 + lb) * 8 + j] = lv;

    // ||centroid||^2 partial -> padded atomic (16 per class)
    float s = val * val;
    #pragma unroll
    for (int m = 1; m < 64; m <<= 1) s += __shfl_xor(s, m, 64);
    if ((t & 63) == 0) atomicAdd(&sqc[c * CSTRIDE], s);
}

// ------- kernel 3: split-bf16 MFMA GEMM + fused softmax --------
// 512 blocks x 256 thr (4 waves) = 2 blocks/CU = 2 waves/SIMD (TLP!).
// Block: 32 rows. Wave (ch,h): col-half ch (4 col-frags), K-half h
// (16 steps of 32 fp32-k). NO LDS / NO syncthreads in the K-loop:
// B-frags register-direct from L2 (512 KiB, XCD-resident), A direct
// from global in frag layout. acc = 2m x 4f = 32 VGPR.
// Epilogue: h-combine (LDS add) + split-softmax merge across ch.
__device__ __forceinline__ void split8(const float4 a0, const float4 a1,
                                       bf16x8& hi, bf16x8& lo) {
    float v[8] = {a0.x, a0.y, a0.z, a0.w, a1.x, a1.y, a1.z, a1.w};
    #pragma unroll
    for (int j = 0; j < 8; ++j) {
        unsigned xb = __float_as_uint(v[j]);
        hi[j] = (short)(xb >> 16);
        float hif = __uint_as_float(xb & 0xffff0000u);
        lo[j] = (short)(__float_as_uint(v[j] - hif) >> 16);
    }
}

__device__ __forceinline__ void load_b(const bf16x8* __restrict__ bHi,
                                       const bf16x8* __restrict__ bLo,
                                       int gs, int ch, int lane,
                                       bf16x8 bh[4], bf16x8 bl[4]) {
    #pragma unroll
    for (int f = 0; f < 4; ++f) {
        int bi = (gs * 8 + ch * 4 + f) * 64 + lane;
        bh[f] = bHi[bi];
        bl[f] = bLo[bi];
    }
}

__device__ __forceinline__ void load_a(const float* __restrict__ e,
                                       int row0, int rlo, int g, int gs,
                                       float4 a0[2], float4 a1[2]) {
    #pragma unroll
    for (int m = 0; m < 2; ++m) {
        const float* ap = e + (size_t)(row0 + m * 16 + rlo) * N_DIM + gs * 32 + g * 8;
        a0[m] = *(const float4*)ap;
        a1[m] = *(const float4*)(ap + 4);
    }
}

__device__ __forceinline__ void step_compute(const float4 a0[2], const float4 a1[2],
                                             const bf16x8 bh[4], const bf16x8 bl[4],
                                             f32x4 acc[2][4]) {
    bf16x8 ah[2], al[2];
    #pragma unroll
    for (int m = 0; m < 2; ++m) split8(a0[m], a1[m], ah[m], al[m]);
    #pragma unroll
    for (int f = 0; f < 4; ++f)
        #pragma unroll
        for (int m = 0; m < 2; ++m) {
            acc[m][f] = __builtin_amdgcn_mfma_f32_16x16x32_bf16(ah[m], bh[f], acc[m][f], 0, 0, 0);
            acc[m][f] = __builtin_amdgcn_mfma_f32_16x16x32_bf16(ah[m], bl[f], acc[m][f], 0, 0, 0);
            acc[m][f] = __builtin_amdgcn_mfma_f32_16x16x32_bf16(al[m], bh[f], acc[m][f], 0, 0, 0);
        }
}

__launch_bounds__(256, 2)
__global__ void k_gemm(const float* __restrict__ e,
                       const unsigned short* __restrict__ bHiU,
                       const unsigned short* __restrict__ bLoU,
                       const float* __restrict__ sqc,
                       float* __restrict__ out) {
    __shared__ f32x4 Lc[2][8][64];     // 16 KiB: h=1 partials per ch
    __shared__ float Lm[2][32];        // per-ch row max
    __shared__ float Ls[2][32];        // per-ch row expsum

    const bf16x8* bHi = (const bf16x8*)bHiU;
    const bf16x8* bLo = (const bf16x8*)bLoU;

    int tid  = threadIdx.x;
    int lane = tid & 63;
    int wid  = tid >> 6;
    int ch   = wid & 1;         // col-half
    int h    = wid >> 1;        // K-half
    int row0 = blockIdx.x * 32;
    int rlo  = lane & 15;
    int g    = lane >> 4;
    int gs0  = h * 16;

    f32x4 acc[2][4];
    #pragma unroll
    for (int m = 0; m < 2; ++m)
        #pragma unroll
        for (int f = 0; f < 4; ++f)
            acc[m][f] = (f32x4)(0.f);

    bf16x8 bhA[4], blA[4], bhB[4], blB[4];
    float4 a0A[2], a1A[2], a0B[2], a1B[2];

    // prologue: step 0 into A-bufs
    load_b(bHi, bLo, gs0, ch, lane, bhA, blA);
    load_a(e, row0, rlo, g, gs0, a0A, a1A);

    // 16 steps, explicit 2-deep ping-pong, guard-free (clamped prefetch)
    #pragma unroll 1
    for (int s = 0; s < 16; s += 2) {
        int sn1 = s + 1;                       // always <= 15
        int sn2 = (s + 2 < 16) ? s + 2 : 15;   // clamp: stray load, never used
        load_b(bHi, bLo, gs0 + sn1, ch, lane, bhB, blB);
        load_a(e, row0, rlo, g, gs0 + sn1, a0B, a1B);
        step_compute(a0A, a1A, bhA, blA, acc);
        load_b(bHi, bLo, gs0 + sn2, ch, lane, bhA, blA);
        load_a(e, row0, rlo, g, gs0 + sn2, a0A, a1A);
        step_compute(a0B, a1B, bhB, blB, acc);
    }

    // ---- h-combine: h=1 dumps, h=0 adds ----
    if (h == 1) {
        #pragma unroll
        for (int m = 0; m < 2; ++m)
            #pragma unroll
            for (int f = 0; f < 4; ++f)
                Lc[ch][m * 4 + f][lane] = acc[m][f];
    }
    __syncthreads();

    float lg[2][4][4];   // raw logits [m][q][f]
    if (h == 0) {
        #pragma unroll
        for (int m = 0; m < 2; ++m)
            #pragma unroll
            for (int f = 0; f < 4; ++f)
                acc[m][f] += Lc[ch][m * 4 + f][lane];

        // logits + per-ch partial max/sum. D-frag: col = ch*64 + f*16 + rlo,
        // row (in block) = m*16 + g*4 + q  (independent of rlo).
        float sq[4];
        #pragma unroll
        for (int f = 0; f < 4; ++f) sq[f] = sqc[(ch * 64 + f * 16 + rlo) * CSTRIDE];

        #pragma unroll
        for (int m = 0; m < 2; ++m)
            #pragma unroll
            for (int q = 0; q < 4; ++q) {
                float mx = -1e30f;
                #pragma unroll
                for (int f = 0; f < 4; ++f) {
                    float l = 2.f * acc[m][f][q] - sq[f];
                    lg[m][q][f] = l;
                    mx = fmaxf(mx, l);
                }
                #pragma unroll
                for (int msk = 1; msk < 16; msk <<= 1) mx = fmaxf(mx, __shfl_xor(mx, msk, 64));
                float sum = 0.f;
                #pragma unroll
                for (int f = 0; f < 4; ++f) sum += __expf(lg[m][q][f] - mx);
                #pragma unroll
                for (int msk = 1; msk < 16; msk <<= 1) sum += __shfl_xor(sum, msk, 64);
                if (rlo == 0) {
                    int r = m * 16 + g * 4 + q;
                    Lm[ch][r] = mx;
                    Ls[ch][r] = sum;
                }
            }
    }
    __syncthreads();

    if (h == 0) {
        // merge the two col-half softmaxes (exact online-softmax merge)
        #pragma unroll
        for (int m = 0; m < 2; ++m)
            #pragma unroll
            for (int q = 0; q < 4; ++q) {
                int r = m * 16 + g * 4 + q;
                float m0 = Lm[0][r], m1 = Lm[1][r];
                float M = fmaxf(m0, m1);
                float S = Ls[0][r] * __expf(m0 - M) + Ls[1][r] * __expf(m1 - M);
                float inv = 1.f / S;
                int row = row0 + r;
                #pragma unroll
                for (int f = 0; f < 4; ++f)
                    out[(size_t)row * N_CLS + ch * 64 + f * 16 + rlo] =
                        __expf(lg[m][q][f] - M) * inv;
            }
    }
}

extern "C" void kernel_launch(void* const* d_in, const int* in_sizes, int n_in,
                              void* d_out, int out_size, void* d_ws, size_t ws_size,
                              hipStream_t stream) {
    const float* e = (const float*)d_in[0];   // embeddings [N, D]
    const float* y = (const float*)d_in[1];   // y_true [N, C]
    float* out = (float*)d_out;               // [N, C]
    char* ws = (char*)d_ws;

    int*            cnt = (int*)(ws + CNT_OFF);
    float*          sqc = (float*)(ws + SQC_OFF);
    int*            rl  = (int*)(ws + RL_OFF);
    unsigned short* bHi = (unsigned short*)(ws + BHI_OFF);
    unsigned short* bLo = (unsigned short*)(ws + BLO_OFF);

    hipMemsetAsync(ws, 0, 32768, stream);  // padded cnt + sqc

    hipLaunchKernelGGL(k_label, dim3((N_ROWS * N_CLS / 4) / 256), dim3(256), 0, stream,
                       y, cnt, rl);
    hipLaunchKernelGGL(k_centroid, dim3(8, N_CLS), dim3(128), 0, stream,
                       e, cnt, rl, bHi, bLo, sqc);
    hipLaunchKernelGGL(k_gemm, dim3(N_ROWS / 32), dim3(256), 0, stream,
                       e, bHi, bLo, sqc, out);
}

// Round 10
// 138.737 us; speedup vs baseline: 1.0191x; 1.0191x over previous
//
#include <hip/hip_runtime.h>

// ProtoNet head: N=16384 rows, C=128 classes, D=1024 dims, fp32 in/out.
// out = softmax_c( 2*dot(e[n], cent[c]) - ||cent[c]||^2 )  (sq_e dropped: shift-invariant)
// cross via split-bf16 MFMA: x=hi+lo; x*c ~= hi*chi + hi*clo + lo*chi  (K'=3072 bf16)
// 3 kernels (NO cooperative launch): label -> centroid -> gemm+softmax.
// k_gemm uses the counted-vmcnt staged pipeline (T3+T4): loads stay in
// flight across s_barrier, vmcnt never drained to 0 inside the K-loop.

#define N_ROWS 16384
#define N_CLS  128
#define N_DIM  1024
#define CSTRIDE 32   // one atomic counter per 128B line

#define CNT_OFF 0         // int cnt[128*32]
#define SQC_OFF 16384     // float sqc[128*32]
#define RL_OFF  32768     // int rowlist[128*256]
#define BHI_OFF 163840    // bf16 B-frags hi: 32 steps * 8 KiB
#define BLO_OFF 425984    // bf16 B-frags lo

typedef __attribute__((ext_vector_type(8))) short bf16x8;
typedef __attribute__((ext_vector_type(4))) float f32x4;

typedef const __attribute__((address_space(1))) void* gas1_cvp;
typedef __attribute__((address_space(3))) void* las3_vp;

__device__ __forceinline__ void gload16(const void* g, void* l) {
    // async global->LDS; HW dest = wave-uniform(lds) + lane*16; global src per-lane
    __builtin_amdgcn_global_load_lds((gas1_cvp)g, (las3_vp)l, 16, 0, 0);
}

__device__ __forceinline__ void split8(const float4 a0, const float4 a1,
                                       bf16x8& hi, bf16x8& lo) {
    float v[8] = {a0.x, a0.y, a0.z, a0.w, a1.x, a1.y, a1.z, a1.w};
    #pragma unroll
    for (int j = 0; j < 8; ++j) {
        unsigned xb = __float_as_uint(v[j]);
        hi[j] = (short)(xb >> 16);
        float hif = __uint_as_float(xb & 0xffff0000u);
        lo[j] = (short)(__float_as_uint(v[j] - hif) >> 16);
    }
}

#define VMW(N) do { asm volatile("s_waitcnt vmcnt(" #N ")" ::: "memory"); \
                    __builtin_amdgcn_sched_barrier(0); } while (0)
#define RBAR() __builtin_amdgcn_s_barrier()

// ---------------- kernel 1: labels -> rowlist + padded counts ----------------
__global__ void k_label(const float* __restrict__ y,
                        int* __restrict__ cnt,
                        int* __restrict__ rowlist) {
    int i = blockIdx.x * blockDim.x + threadIdx.x;   // float4 index over N*C/4
    float4 v = ((const float4*)y)[i];
    int base = i * 4;
    int row = base >> 7;
    int cb  = base & (N_CLS - 1);
    if (v.x > 0.5f) { int s = atomicAdd(&cnt[(cb + 0) * CSTRIDE], 1); if (s < 256) rowlist[(cb + 0) * 256 + s] = row; }
    if (v.y > 0.5f) { int s = atomicAdd(&cnt[(cb + 1) * CSTRIDE], 1); if (s < 256) rowlist[(cb + 1) * 256 + s] = row; }
    if (v.z > 0.5f) { int s = atomicAdd(&cnt[(cb + 2) * CSTRIDE], 1); if (s < 256) rowlist[(cb + 2) * 256 + s] = row; }
    if (v.w > 0.5f) { int s = atomicAdd(&cnt[(cb + 3) * CSTRIDE], 1); if (s < 256) rowlist[(cb + 3) * 256 + s] = row; }
}

// ---- kernel 2: centroids -> packed bf16 hi/lo B-fragments + sq_c ----
// B-frag for mfma_f32_16x16x32_bf16: elem j of lane l, step gs, col-frag f
//   = B[k = gs*32 + (l>>4)*8 + j][col = f*16 + (l&15)]; step block is 8 KiB contiguous.
__global__ void k_centroid(const float* __restrict__ e,
                           const int* __restrict__ cnt,
                           const int* __restrict__ rowlist,
                           unsigned short* __restrict__ bHi,
                           unsigned short* __restrict__ bLo,
                           float* __restrict__ sqc) {
    int c  = blockIdx.y;
    int ch = blockIdx.x;
    int t  = threadIdx.x;
    int d  = ch * 128 + t;
    int n  = cnt[c * CSTRIDE];
    if (n > 256) n = 256;
    const int* rl = rowlist + c * 256;

    float acc = 0.f;
    int i = 0;
    for (; i + 16 <= n; i += 16) {
        float v[16];
        #pragma unroll
        for (int u = 0; u < 16; ++u) v[u] = e[(size_t)rl[i + u] * N_DIM + d];
        float s0 = ((v[0] + v[1]) + (v[2] + v[3])) + ((v[4] + v[5]) + (v[6] + v[7]));
        float s1 = ((v[8] + v[9]) + (v[10] + v[11])) + ((v[12] + v[13]) + (v[14] + v[15]));
        acc += s0 + s1;
    }
    for (; i < n; ++i) acc += e[(size_t)rl[i] * N_DIM + d];

    float val = (n > 0) ? acc / (float)n : 0.f;

    unsigned xb = __float_as_uint(val);
    unsigned short hv = (unsigned short)(xb >> 16);
    float hif = __uint_as_float(xb & 0xffff0000u);
    unsigned short lv = (unsigned short)(__float_as_uint(val - hif) >> 16);

    int gs = d >> 5;
    int g  = (d >> 3) & 3;
    int j  = d & 7;
    int f  = c >> 4;
    int lb = g * 16 + (c & 15);
    bHi[((gs * 8 + f) * 64 + lb) * 8 + j] = hv;
    bLo[((gs * 8 + f) * 64 + lb) * 8 + j] = lv;

    float s = val * val;
    #pragma unroll
    for (int m = 1; m < 64; m <<= 1) s += __shfl_xor(s, m, 64);
    if ((t & 63) == 0) atomicAdd(&sqc[c * CSTRIDE], s);
}

// ------- kernel 3: counted-vmcnt MFMA GEMM + fused softmax --------
// 256 blocks x 512 thr (8 waves = 2/SIMD). Wave (rt,ch): 16-row tile rt,
// col-half ch, FULL K (32 steps of 32 fp32-k). B staged into 4-slot LDS
// ring via global_load_lds; per body: [A(s+1)] [vmcnt(4)] [s_barrier]
// [stage(s+3)] [compute(s)] — 4 loads stay in flight across each barrier.

// stage step s's B (8 KiB hi + 8 KiB lo) into slot s&3; each wave 2 KiB
__device__ __forceinline__ void g_stage(const char* bHiB, const char* bLoB,
                                        char* smem, int s, int wid, int lane) {
    char* slot = smem + (s & 3) * 16384;
    #pragma unroll
    for (int p = 0; p < 2; ++p) {
        int c = wid * 2 + p;   // 0..15: c<8 -> hi frag c ; else lo frag c-8
        const char* src = (c < 8) ? (bHiB + (size_t)s * 8192 + c * 1024)
                                  : (bLoB + (size_t)s * 8192 + (c - 8) * 1024);
        gload16(src + lane * 16, slot + c * 1024);
    }
}

__device__ __forceinline__ void g_compute(const char* smem, int s, int ch, int lane,
                                          const float4& a0, const float4& a1,
                                          f32x4 acc[4]) {
    bf16x8 ah, al;
    split8(a0, a1, ah, al);
    const char* slot = smem + (s & 3) * 16384;
    #pragma unroll
    for (int f = 0; f < 4; ++f) {
        int fp = ch * 4 + f;
        bf16x8 bh = *(const bf16x8*)(slot + fp * 1024 + lane * 16);
        bf16x8 bl = *(const bf16x8*)(slot + 8192 + fp * 1024 + lane * 16);
        acc[f] = __builtin_amdgcn_mfma_f32_16x16x32_bf16(ah, bh, acc[f], 0, 0, 0);
        acc[f] = __builtin_amdgcn_mfma_f32_16x16x32_bf16(ah, bl, acc[f], 0, 0, 0);
        acc[f] = __builtin_amdgcn_mfma_f32_16x16x32_bf16(al, bh, acc[f], 0, 0, 0);
    }
}

__launch_bounds__(512, 2)
__global__ void k_gemm(const float* __restrict__ e,
                       const unsigned short* __restrict__ bHiU,
                       const unsigned short* __restrict__ bLoU,
                       const float* __restrict__ sqc,
                       float* __restrict__ outp) {
    __shared__ char smem[65536];   // 4 staging slots x 16 KiB; epilogue reuse

    const char* bHiB = (const char*)bHiU;
    const char* bLoB = (const char*)bLoU;

    int tid  = threadIdx.x;
    int blk  = blockIdx.x;
    int lane = tid & 63;
    int wid  = tid >> 6;       // 8 waves
    int rt   = wid >> 1;       // 0..3: 16-row tile
    int ch   = wid & 1;        // col half (4 frags)
    int rlo  = lane & 15;
    int g    = lane >> 4;
    int row0 = blk * 64 + rt * 16;
    const float* arow = e + (size_t)(row0 + rlo) * N_DIM + g * 8;

    f32x4 acc[4];
    #pragma unroll
    for (int f = 0; f < 4; ++f) acc[f] = (f32x4)(0.f);

    float4 aE0, aE1, aO0, aO1;

    // prologue: slots 0..2 staged, A(0)->E  (8 vmem ops issued)
    g_stage(bHiB, bLoB, smem, 0, wid, lane);
    aE0 = *(const float4*)(arow);
    aE1 = *(const float4*)(arow + 4);
    g_stage(bHiB, bLoB, smem, 1, wid, lane);
    g_stage(bHiB, bLoB, smem, 2, wid, lane);

    // body(0): A(1)->O ; vmcnt(6) retires st0+A0 ; BAR ; st3 ; compute0
    aO0 = *(const float4*)(arow + 32);
    aO1 = *(const float4*)(arow + 36);
    VMW(6); RBAR();
    g_stage(bHiB, bLoB, smem, 3, wid, lane);
    g_compute(smem, 0, ch, lane, aE0, aE1, acc);

    // steady: bodies s=1..28 — [A(s+1)] [vmcnt(4)] [BAR] [stage(s+3)] [compute(s)]
    #pragma unroll 1
    for (int s2 = 1; s2 < 28; s2 += 2) {
        aE0 = *(const float4*)(arow + (s2 + 1) * 32);
        aE1 = *(const float4*)(arow + (s2 + 1) * 32 + 4);
        VMW(4); RBAR();
        g_stage(bHiB, bLoB, smem, s2 + 3, wid, lane);
        g_compute(smem, s2, ch, lane, aO0, aO1, acc);

        aO0 = *(const float4*)(arow + (s2 + 2) * 32);
        aO1 = *(const float4*)(arow + (s2 + 2) * 32 + 4);
        VMW(4); RBAR();
        g_stage(bHiB, bLoB, smem, s2 + 4, wid, lane);
        g_compute(smem, s2 + 1, ch, lane, aE0, aE1, acc);
    }
    // tail: s=29,30,31 (slot 31 staged in body 28)
    aE0 = *(const float4*)(arow + 30 * 32);
    aE1 = *(const float4*)(arow + 30 * 32 + 4);
    VMW(4); RBAR();
    g_compute(smem, 29, ch, lane, aO0, aO1, acc);

    aO0 = *(const float4*)(arow + 31 * 32);
    aO1 = *(const float4*)(arow + 31 * 32 + 4);
    VMW(2); RBAR();
    g_compute(smem, 30, ch, lane, aE0, aE1, acc);

    VMW(0); RBAR();
    g_compute(smem, 31, ch, lane, aO0, aO1, acc);

    __syncthreads();   // loop done; repurpose smem for softmax merge

    // epilogue: logits + ch-split softmax merge.
    // D-frag: col = (ch*4+f)*16 + rlo ; row-in-block = rt*16 + g*4 + q
    float* Lm = (float*)smem;          // [2][64]
    float* Ls = (float*)smem + 128;    // [2][64]

    float sq[4];
    #pragma unroll
    for (int f = 0; f < 4; ++f) sq[f] = sqc[((ch * 4 + f) * 16 + rlo) * CSTRIDE];

    float lg[4][4];   // [q][f]
    #pragma unroll
    for (int q = 0; q < 4; ++q) {
        float mx = -1e30f;
        #pragma unroll
        for (int f = 0; f < 4; ++f) {
            float l = 2.f * acc[f][q] - sq[f];
            lg[q][f] = l;
            mx = fmaxf(mx, l);
        }
        #pragma unroll
        for (int msk = 1; msk < 16; msk <<= 1) mx = fmaxf(mx, __shfl_xor(mx, msk, 64));
        float sum = 0.f;
        #pragma unroll
        for (int f = 0; f < 4; ++f) sum += __expf(lg[q][f] - mx);
        #pragma unroll
        for (int msk = 1; msk < 16; msk <<= 1) sum += __shfl_xor(sum, msk, 64);
        if (rlo == 0) {
            int r = rt * 16 + g * 4 + q;
            Lm[ch * 64 + r] = mx;
            Ls[ch * 64 + r] = sum;
        }
    }
    __syncthreads();

    #pragma unroll
    for (int q = 0; q < 4; ++q) {
        int r = rt * 16 + g * 4 + q;
        float m0 = Lm[r], m1 = Lm[64 + r];
        float M = fmaxf(m0, m1);
        float S = Ls[r] * __expf(m0 - M) + Ls[64 + r] * __expf(m1 - M);
        float inv = 1.f / S;
        int row = blk * 64 + r;
        #pragma unroll
        for (int f = 0; f < 4; ++f)
            outp[(size_t)row * N_CLS + (ch * 4 + f) * 16 + rlo] =
                __expf(lg[q][f] - M) * inv;
    }
}

extern "C" void kernel_launch(void* const* d_in, const int* in_sizes, int n_in,
                              void* d_out, int out_size, void* d_ws, size_t ws_size,
                              hipStream_t stream) {
    const float* e = (const float*)d_in[0];
    const float* y = (const float*)d_in[1];
    float* outp = (float*)d_out;
    char* ws = (char*)d_ws;

    int*            cnt = (int*)(ws + CNT_OFF);
    float*          sqc = (float*)(ws + SQC_OFF);
    int*            rl  = (int*)(ws + RL_OFF);
    unsigned short* bHi = (unsigned short*)(ws + BHI_OFF);
    unsigned short* bLo = (unsigned short*)(ws + BLO_OFF);

    hipMemsetAsync(ws, 0, 32768, stream);  // padded cnt + sqc

    hipLaunchKernelGGL(k_label, dim3((N_ROWS * N_CLS / 4) / 256), dim3(256), 0, stream,
                       y, cnt, rl);
    hipLaunchKernelGGL(k_centroid, dim3(8, N_CLS), dim3(128), 0, stream,
                       e, cnt, rl, bHi, bLo, sqc);
    hipLaunchKernelGGL(k_gemm, dim3(N_ROWS / 64), dim3(512), 0, stream,
                       e, bHi, bLo, sqc, outp);
}